// Round 10
// baseline (239.079 us; speedup 1.0000x reference)
//
#include <hip/hip_runtime.h>
#include <hip/hip_bf16.h>
#include <stdint.h>
#include <math.h>

#define EPS_CELL 1e-6f
#define LN_EPS   1e-5f

typedef short short8 __attribute__((ext_vector_type(8)));
typedef float f32x4 __attribute__((ext_vector_type(4)));
typedef unsigned short ushort;

__device__ __forceinline__ ushort f2bf(float f) {
    union { float f; uint32_t u; } v; v.f = f;
    uint32_t r = v.u + 0x7FFFu + ((v.u >> 16) & 1u);  // round-to-nearest-even
    return (ushort)(r >> 16);
}
__device__ __forceinline__ float bfbits2f(uint32_t hi16_in_place) {
    union { uint32_t u; float f; } v; v.u = hi16_in_place;
    return v.f;
}

// fast math: single-instruction HW transcendentals
__device__ __forceinline__ float fexp(float x)  { return __builtin_amdgcn_exp2f(x * 1.4426950408889634f); }
__device__ __forceinline__ float frcp(float x)  { return __builtin_amdgcn_rcpf(x); }
__device__ __forceinline__ float frsq(float x)  { return __builtin_amdgcn_rsqf(x); }
__device__ __forceinline__ float ftanh(float x) {
    float xc = fminf(fmaxf(x, -15.f), 15.f);
    float t  = fexp(2.f * xc);
    return (t - 1.f) * frcp(t + 1.f);
}
__device__ __forceinline__ float fsigm(float x) { return frcp(1.f + fexp(-x)); }

// ---------------------------------------------------------------- merged cast f32->bf16 (4 regions, 1 dispatch)
// region sizes all multiples of 2048 -> no block straddles a boundary.
__global__ __launch_bounds__(256) void cast_all(
        const float* __restrict__ x,  const float* __restrict__ h,
        const float* __restrict__ wx, const float* __restrict__ wh,
        ushort* __restrict__ xb, ushort* __restrict__ hb,
        ushort* __restrict__ wxb, ushort* __restrict__ whb) {
    long i = ((long)blockIdx.x * 256 + threadIdx.x) * 8;
    const float* src; ushort* dst; long off;
    if      (i <  4194304L) { src = x;  dst = xb;  off = i; }
    else if (i < 12582912L) { src = h;  dst = hb;  off = i - 4194304L; }
    else if (i < 14680064L) { src = wx; dst = wxb; off = i - 12582912L; }
    else                    { src = wh; dst = whb; off = i - 14680064L; }
    const float4* p = (const float4*)(src + off);
    float4 a = p[0], b = p[1];
    uint4 r;
    r.x = (uint32_t)f2bf(a.x) | ((uint32_t)f2bf(a.y) << 16);
    r.y = (uint32_t)f2bf(a.z) | ((uint32_t)f2bf(a.w) << 16);
    r.z = (uint32_t)f2bf(b.x) | ((uint32_t)f2bf(b.y) << 16);
    r.w = (uint32_t)f2bf(b.z) | ((uint32_t)f2bf(b.w) << 16);
    *(uint4*)(dst + off) = r;
}

// ================================================================ 256x256 8-phase GEMM
// Pinned waits (r2-r5 known-good codegen). g1024 runs as two 256-block
// single-wave dispatches (measured faster); g512 as one 512-block dispatch.
#define BAR()        __builtin_amdgcn_s_barrier()
#define SPRIO(x)     __builtin_amdgcn_s_setprio(x)
#define WAIT_LGKM0() do { asm volatile("s_waitcnt lgkmcnt(0)" ::: "memory"); \
                          __builtin_amdgcn_sched_barrier(0); } while (0)
#define WAIT_VM6()   do { asm volatile("s_waitcnt vmcnt(6)" ::: "memory"); \
                          __builtin_amdgcn_sched_barrier(0); } while (0)
#define WAIT_VM0()   do { asm volatile("s_waitcnt vmcnt(0)" ::: "memory"); \
                          __builtin_amdgcn_sched_barrier(0); } while (0)

template<int K>
__global__ __launch_bounds__(512, 2) void gemm256_8ph(
        const ushort* __restrict__ Ag,   // [M, K]
        const ushort* __restrict__ Bg,   // [GN, K]
        const float*  __restrict__ bias, // [GN]
        ushort* __restrict__ C,          // [M, GN]
        int GN, int m_base) {
    constexpr int NT = K / 64;           // K-tiles
    constexpr int NP = NT / 2;           // pair iterations

    __shared__ ushort lds[65536];        // 128 KiB: buf0{A,B} buf1{A,B}

    const int t    = threadIdx.x;        // 0..511
    const int lane = t & 63;
    const int w    = t >> 6;             // 0..7
    const int wr   = w >> 2;             // 0..1 (M half)
    const int wc   = w & 3;              // 0..3 (N quarter)
    const int ln   = lane & 15;
    const int hi   = lane >> 4;          // 0..3
    const int sx   = ln & 7;             // read-side XOR key (row&7 == ln&7)

    // XCD-aware bijective swizzle (gridDim.x % 8 == 0)
    const int bid = blockIdx.x;
    const int cpx = gridDim.x >> 3;
    const int wg  = (bid & 7) * cpx + (bid >> 3);
    const int n0  = (wg & 15) * 256;     // GN/256 = 16
    const int m0  = (wg >> 4) * 256 + m_base;

    // staging: thread t stages 16B; dst LINEAR; source col pre-swizzled.
    const int trow = t >> 3;                          // 0..63 within a 64-row load
    const int scol = (((t & 7) ^ (trow & 7)) * 8);    // shorts

#define STG_A(buf, j, kb) __builtin_amdgcn_global_load_lds( \
    (const __attribute__((address_space(1))) void*)(Ag + (size_t)(m0 + (j)*64 + trow) * K + (kb) + scol), \
    (__attribute__((address_space(3))) void*)(lds + (buf)*32768 + (j)*4096 + t*8), 16, 0, 0)
#define STG_B(buf, j, kb) __builtin_amdgcn_global_load_lds( \
    (const __attribute__((address_space(1))) void*)(Bg + (size_t)(n0 + (j)*64 + trow) * K + (kb) + scol), \
    (__attribute__((address_space(3))) void*)(lds + (buf)*32768 + 16384 + (j)*4096 + t*8), 16, 0, 0)

    // swizzled read offsets (shorts)
    const int ca0  = ((0 + hi) ^ sx) * 8;             // kk = 0
    const int ca1  = ((4 + hi) ^ sx) * 8;             // kk = 1
    const int arow = (wr * 16 + ln) * 64;             // + m*2048 (A frag m: rows m*32+wr*16+ln)
    const int brow = (wc * 16 + ln) * 64 + 16384;     // + n*4096 (B frag n: rows n*64+wc*16+ln)

    short8 af[2][4], bf0[2][2], bf1[2][2];
    f32x4  acc[8][4] = {};

#define LD_A(buf, mbase) do { _Pragma("unroll") for (int m = 0; m < 4; ++m) { \
    af[0][m] = *(const short8*)&lds[(buf)*32768 + arow + ((mbase)+m)*2048 + ca0]; \
    af[1][m] = *(const short8*)&lds[(buf)*32768 + arow + ((mbase)+m)*2048 + ca1]; } } while (0)
#define LD_B(dst, buf, nbase) do { _Pragma("unroll") for (int n = 0; n < 2; ++n) { \
    dst[0][n] = *(const short8*)&lds[(buf)*32768 + brow + ((nbase)+n)*4096 + ca0]; \
    dst[1][n] = *(const short8*)&lds[(buf)*32768 + brow + ((nbase)+n)*4096 + ca1]; } } while (0)
#define MMQ(mb, nb, B_) do { _Pragma("unroll") for (int kk = 0; kk < 2; ++kk) \
    _Pragma("unroll") for (int m = 0; m < 4; ++m) \
    _Pragma("unroll") for (int n = 0; n < 2; ++n) \
        acc[(mb)+m][(nb)+n] = __builtin_amdgcn_mfma_f32_16x16x32_bf16( \
            af[kk][m], B_[kk][n], acc[(mb)+m][(nb)+n], 0, 0, 0); } while (0)

    // ---- prologue: buf0 = tile0 (8 loads), buf1 = tile1 Bh0,Ah0,Bh1 (6 loads)
    STG_B(0,0,0);  STG_B(0,1,0);
    STG_A(0,0,0);  STG_A(0,1,0);
    STG_B(0,2,0);  STG_B(0,3,0);
    STG_A(0,2,0);  STG_A(0,3,0);
    STG_B(1,0,64); STG_B(1,1,64);
    STG_A(1,0,64); STG_A(1,1,64);
    STG_B(1,2,64); STG_B(1,3,64);
    WAIT_VM6(); BAR();

    // ---- main loop: iter p computes tiles 2p (buf0) and 2p+1 (buf1)
    for (int p = 0; p < NP; ++p) {
        const int k1 = (2*p + 1) * 64;
        const int t2 = (2*p + 2 < NT) ? (2*p + 2) : (2*p);
        const int t3 = (2*p + 3 < NT) ? (2*p + 3) : (2*p + 1);
        const int k2 = t2 * 64, k3 = t3 * 64;

        // P1: read buf0 Ah0+Bh0; stage buf1.Ah1
        LD_A(0, 0); LD_B(bf0, 0, 0);
        STG_A(1,2,k1); STG_A(1,3,k1);
        BAR(); WAIT_LGKM0();
        SPRIO(1); MMQ(0,0,bf0); SPRIO(0); BAR();
        // P2: read buf0 Bh1; stage buf0'.Bh0
        LD_B(bf1, 0, 2);
        STG_B(0,0,k2); STG_B(0,1,k2);
        BAR(); WAIT_LGKM0();
        SPRIO(1); MMQ(0,2,bf1); SPRIO(0); BAR();
        // P3: read buf0 Ah1; stage buf0'.Ah0
        LD_A(0, 4);
        STG_A(0,0,k2); STG_A(0,1,k2);
        BAR(); WAIT_LGKM0();
        SPRIO(1); MMQ(4,0,bf0); SPRIO(0); BAR();
        // P4: stage buf0'.Bh1; counted wait -> buf1 fully landed
        STG_B(0,2,k2); STG_B(0,3,k2);
        BAR();
        SPRIO(1); MMQ(4,2,bf1); SPRIO(0);
        WAIT_VM6(); BAR();
        // P5: read buf1 Ah0+Bh0; stage buf0'.Ah1
        LD_A(1, 0); LD_B(bf0, 1, 0);
        STG_A(0,2,k2); STG_A(0,3,k2);
        BAR(); WAIT_LGKM0();
        SPRIO(1); MMQ(0,0,bf0); SPRIO(0); BAR();
        // P6: read buf1 Bh1; stage buf1'.Bh0
        LD_B(bf1, 1, 2);
        STG_B(1,0,k3); STG_B(1,1,k3);
        BAR(); WAIT_LGKM0();
        SPRIO(1); MMQ(0,2,bf1); SPRIO(0); BAR();
        // P7: read buf1 Ah1; stage buf1'.Ah0
        LD_A(1, 4);
        STG_A(1,0,k3); STG_A(1,1,k3);
        BAR(); WAIT_LGKM0();
        SPRIO(1); MMQ(4,0,bf0); SPRIO(0); BAR();
        // P8: stage buf1'.Bh1; counted wait -> buf0' fully landed
        STG_B(1,2,k3); STG_B(1,3,k3);
        BAR();
        SPRIO(1); MMQ(4,2,bf1); SPRIO(0);
        WAIT_VM6(); BAR();
    }

    // ---- epilogue: stage C-tile in LDS (bf16, swizzled), then coalesced stores.
    WAIT_VM0();
    BAR();
#pragma unroll
    for (int n = 0; n < 4; ++n) {
        int cl   = n * 64 + wc * 16 + ln;
        float bv = bias[n0 + cl];
#pragma unroll
        for (int m = 0; m < 8; ++m) {
#pragma unroll
            for (int r = 0; r < 4; ++r) {
                int row = m * 32 + wr * 16 + hi * 4 + r;
                int sc  = (cl & 7) + ((((cl >> 3) ^ (row & 7))) << 3);
                lds[row * 256 + sc] = f2bf(acc[m][n][r] + bv);
            }
        }
    }
    BAR();
    {
        const int rr = t >> 5;
        const int oc = (t & 31) * 8;
#pragma unroll
        for (int i = 0; i < 16; ++i) {
            int row = i * 16 + rr;
            int sc  = (((oc >> 3) ^ (row & 7)) << 3);
            uint4 vv = *(const uint4*)&lds[row * 256 + sc];
            *(uint4*)(C + (size_t)(m0 + row) * GN + n0 + oc) = vv;
        }
    }
#undef STG_A
#undef STG_B
#undef LD_A
#undef LD_B
#undef MMQ
}

// ---------------------------------------------------------------- per-row reduce (4 waves of a row group)
// butterfly in-wave, cross-wave via per-row/per-round LDS slice, ONE barrier.
template<int NV>
__device__ __forceinline__ void row_reduce(float* v, float* slice) {
    const int lane = threadIdx.x & 63;
    const int wir  = (threadIdx.x >> 6) & 3;   // wave index within row group
#pragma unroll
    for (int i = 0; i < NV; ++i) {
        float s = v[i];
#pragma unroll
        for (int m = 32; m > 0; m >>= 1) s += __shfl_xor(s, m, 64);
        if (lane == 0) slice[i * 4 + wir] = s;
    }
    __syncthreads();
#pragma unroll
    for (int i = 0; i < NV; ++i)
        v[i] = slice[i * 4 + 0] + slice[i * 4 + 1] + slice[i * 4 + 2] + slice[i * 4 + 3];
}

// ---------------------------------------------------------------- fused cell: 4 rows / 1024-thread block
// Row group rr = waves 4rr..4rr+3 handles row blockIdx.x*4+rr; thread owns
// elements [tt*4, tt*4+4) of each gate quarter. gamma/beta lines shared by
// all 4 row groups (L1 amortization); 4 block barriers total.
__global__ __launch_bounds__(1024) void fused_cell4(
        const ushort* __restrict__ U, const ushort* __restrict__ V,
        const float* __restrict__ c_prev,
        const float* __restrict__ g_in, const float* __restrict__ b_in,
        const float* __restrict__ g_hu, const float* __restrict__ b_hu,
        const float* __restrict__ g_c,  const float* __restrict__ b_c,
        const float* __restrict__ g_h,  const float* __restrict__ b_h,
        float* __restrict__ out_h, float* __restrict__ out_c) {
    __shared__ float sred[4][4][16];           // [row][round][slot]
    const int t  = threadIdx.x;
    const int rr = t >> 8;                     // row within block
    const int tt = t & 255;
    const int r  = blockIdx.x * 4 + rr;
    const size_t rowG = (size_t)r * 4096;
    const size_t rowH = (size_t)r * 1024;
    const int c0 = tt * 4;

    // --- issue all row-data loads up front
    uint2 uu[4], vv[4];
#pragma unroll
    for (int q = 0; q < 4; ++q) {
        uu[q] = *(const uint2*)(U + rowG + q * 1024 + c0);
        vv[q] = *(const uint2*)(V + rowG + q * 1024 + c0);
    }
    float4 cp4 = *(const float4*)(c_prev + rowH + c0);
    float4 gc4 = *(const float4*)(g_c + c0);
    float4 bc4 = *(const float4*)(b_c + c0);
    float4 gh4 = *(const float4*)(g_h + c0);
    float4 bh4 = *(const float4*)(b_h + c0);

    float uq[4][4], vq[4][4];
#pragma unroll
    for (int q = 0; q < 4; ++q) {
        uq[q][0] = bfbits2f(uu[q].x << 16); uq[q][1] = bfbits2f(uu[q].x & 0xFFFF0000u);
        uq[q][2] = bfbits2f(uu[q].y << 16); uq[q][3] = bfbits2f(uu[q].y & 0xFFFF0000u);
        vq[q][0] = bfbits2f(vv[q].x << 16); vq[q][1] = bfbits2f(vv[q].x & 0xFFFF0000u);
        vq[q][2] = bfbits2f(vv[q].y << 16); vq[q][3] = bfbits2f(vv[q].y & 0xFFFF0000u);
    }

    // --- R1: LN stats over 4096 for u and v
    float red[4] = {0.f, 0.f, 0.f, 0.f};
#pragma unroll
    for (int q = 0; q < 4; ++q)
#pragma unroll
        for (int j = 0; j < 4; ++j) {
            red[0] += uq[q][j]; red[1] += uq[q][j] * uq[q][j];
            red[2] += vq[q][j]; red[3] += vq[q][j] * vq[q][j];
        }
    row_reduce<4>(red, sred[rr][0]);
    const float inv4096 = 1.f / 4096.f;
    float mu_u = red[0] * inv4096, mu_v = red[2] * inv4096;
    float rs_u = frsq(red[1] * inv4096 - mu_u * mu_u + LN_EPS);
    float rs_v = frsq(red[3] * inv4096 - mu_v * mu_v + LN_EPS);

    // --- gates = LN(u)*g1+b1 + LN(v)*g2+b2
    float gate[4][4];
#pragma unroll
    for (int q = 0; q < 4; ++q) {
        int idx = q * 1024 + c0;
        float4 gi_ = *(const float4*)(g_in + idx);
        float4 bi_ = *(const float4*)(b_in + idx);
        float4 gh_ = *(const float4*)(g_hu + idx);
        float4 bh_ = *(const float4*)(b_hu + idx);
        float gia[4] = {gi_.x, gi_.y, gi_.z, gi_.w};
        float bia[4] = {bi_.x, bi_.y, bi_.z, bi_.w};
        float gha[4] = {gh_.x, gh_.y, gh_.z, gh_.w};
        float bha[4] = {bh_.x, bh_.y, bh_.z, bh_.w};
#pragma unroll
        for (int j = 0; j < 4; ++j) {
            float zu = (uq[q][j] - mu_u) * rs_u;
            float zv = (vq[q][j] - mu_v) * rs_v;
            gate[q][j] = zu * gia[j] + bia[j] + zv * gha[j] + bha[j];
        }
    }

    // --- R2: exp sums (shift-invariant softmax; +-20 inf-guard never binds)
    float ei[4], ef[4];
    red[0] = 0.f; red[1] = 0.f;
#pragma unroll
    for (int q = 0; q < 4; ++q) {
        ei[q] = fexp(fminf(fmaxf(gate[0][q], -20.f), 20.f));
        ef[q] = fexp(fminf(fmaxf(gate[1][q], -20.f), 20.f));
        red[0] += ei[q]; red[1] += ef[q];
    }
    row_reduce<2>(red, sred[rr][1]);
    float inv_si = frcp(red[0] + EPS_CELL);
    float inv_sf = frcp(red[1] + EPS_CELL);

    // --- cell update
    float cprev[4] = {cp4.x, cp4.y, cp4.z, cp4.w};
    float cpv[4];
    red[0] = 0.f; red[1] = 0.f;
#pragma unroll
    for (int q = 0; q < 4; ++q) {
        float in_ = ei[q] * inv_si;
        float fn_ = ef[q] * inv_sf;
        float den = frcp(in_ + fn_ + EPS_CELL);
        cpv[q] = fn_ * den * cprev[q] + in_ * den * ftanh(gate[2][q]);
        red[0] += cpv[q]; red[1] += cpv[q] * cpv[q];
    }
    row_reduce<2>(red, sred[rr][2]);
    const float inv1024 = 1.f / 1024.f;
    float mu_c = red[0] * inv1024;
    float rs_c = frsq(red[1] * inv1024 - mu_c * mu_c + LN_EPS);

    // --- c-LN, write c, tanh stats
    float cv[4], th[4];
    {
        float gca[4] = {gc4.x, gc4.y, gc4.z, gc4.w};
        float bca[4] = {bc4.x, bc4.y, bc4.z, bc4.w};
        red[0] = 0.f; red[1] = 0.f;
#pragma unroll
        for (int q = 0; q < 4; ++q) {
            cv[q] = (cpv[q] - mu_c) * rs_c * gca[q] + bca[q];
            th[q] = ftanh(cv[q]);
            red[0] += th[q]; red[1] += th[q] * th[q];
        }
    }
    {
        float4 o; o.x = cv[0]; o.y = cv[1]; o.z = cv[2]; o.w = cv[3];
        *(float4*)(out_c + rowH + c0) = o;
    }
    row_reduce<2>(red, sred[rr][3]);
    float mu_t = red[0] * inv1024;
    float rs_t = frsq(red[1] * inv1024 - mu_t * mu_t + LN_EPS);

    // --- h output
    {
        float gha[4] = {gh4.x, gh4.y, gh4.z, gh4.w};
        float bha[4] = {bh4.x, bh4.y, bh4.z, bh4.w};
        float hv[4];
#pragma unroll
        for (int q = 0; q < 4; ++q) {
            float co = (th[q] - mu_t) * rs_t * gha[q] + bha[q];
            hv[q] = fsigm(gate[3][q]) * co;
        }
        float4 o; o.x = hv[0]; o.y = hv[1]; o.z = hv[2]; o.w = hv[3];
        *(float4*)(out_h + rowH + c0) = o;
    }
}

// ---------------------------------------------------------------- launch
extern "C" void kernel_launch(void* const* d_in, const int* in_sizes, int n_in,
                              void* d_out, int out_size, void* d_ws, size_t ws_size,
                              hipStream_t stream) {
    const float* x       = (const float*)d_in[0];
    const float* h_prev  = (const float*)d_in[1];
    const float* c_prev  = (const float*)d_in[2];
    const float* Wx      = (const float*)d_in[3];
    const float* bx      = (const float*)d_in[4];
    const float* Wh      = (const float*)d_in[5];
    const float* bh      = (const float*)d_in[6];
    const float* ln_in_g = (const float*)d_in[7];
    const float* ln_in_b = (const float*)d_in[8];
    const float* ln_hu_g = (const float*)d_in[9];
    const float* ln_hu_b = (const float*)d_in[10];
    const float* ln_c_g  = (const float*)d_in[11];
    const float* ln_c_b  = (const float*)d_in[12];
    const float* ln_h_g  = (const float*)d_in[13];
    const float* ln_h_b  = (const float*)d_in[14];

    const int B = 8192, Din = 512, H = 1024, G = 4096;

    ushort* xb  = (ushort*)d_ws;                  // B*Din
    ushort* hb  = xb  + (size_t)B * Din;          // B*H
    ushort* wxb = hb  + (size_t)B * H;            // G*Din
    ushort* whb = wxb + (size_t)G * Din;          // G*H
    ushort* U   = whb + (size_t)G * H;            // B*G
    ushort* V   = U   + (size_t)B * G;            // B*G

    // one merged cast dispatch: (B*Din + B*H + G*Din + G*H) / 2048 blocks
    cast_all<<<9216, 256, 0, stream>>>(x, h_prev, Wx, Wh, xb, hb, wxb, whb);

    // g512: one full-grid dispatch; g1024: two 256-block single-wave dispatches.
    gemm256_8ph<512> <<<dim3(512), 512, 0, stream>>>(xb, wxb, bx, U, G, 0);
    gemm256_8ph<1024><<<dim3(256), 512, 0, stream>>>(hb, whb, bh, V, G, 0);
    gemm256_8ph<1024><<<dim3(256), 512, 0, stream>>>(hb, whb, bh, V, G, 4096);

    float* out_h = (float*)d_out;
    float* out_c = out_h + (size_t)B * H;
    fused_cell4<<<B / 4, 1024, 0, stream>>>(U, V, c_prev,
                                            ln_in_g, ln_in_b, ln_hu_g, ln_hu_b,
                                            ln_c_g, ln_c_b, ln_h_g, ln_h_b,
                                            out_h, out_c);
}

// Round 11
// 213.768 us; speedup vs baseline: 1.1184x; 1.1184x over previous
//
#include <hip/hip_runtime.h>
#include <hip/hip_bf16.h>
#include <stdint.h>
#include <math.h>

#define EPS_CELL 1e-6f
#define LN_EPS   1e-5f

typedef short short8 __attribute__((ext_vector_type(8)));
typedef float f32x4 __attribute__((ext_vector_type(4)));
typedef unsigned short ushort;

__device__ __forceinline__ ushort f2bf(float f) {
    union { float f; uint32_t u; } v; v.f = f;
    uint32_t r = v.u + 0x7FFFu + ((v.u >> 16) & 1u);  // round-to-nearest-even
    return (ushort)(r >> 16);
}
__device__ __forceinline__ float bfbits2f(uint32_t hi16_in_place) {
    union { uint32_t u; float f; } v; v.u = hi16_in_place;
    return v.f;
}

// fast math: single-instruction HW transcendentals
__device__ __forceinline__ float fexp(float x)  { return __builtin_amdgcn_exp2f(x * 1.4426950408889634f); }
__device__ __forceinline__ float frcp(float x)  { return __builtin_amdgcn_rcpf(x); }
__device__ __forceinline__ float frsq(float x)  { return __builtin_amdgcn_rsqf(x); }
__device__ __forceinline__ float ftanh(float x) {
    float xc = fminf(fmaxf(x, -15.f), 15.f);
    float t  = fexp(2.f * xc);
    return (t - 1.f) * frcp(t + 1.f);
}
__device__ __forceinline__ float fsigm(float x) { return frcp(1.f + fexp(-x)); }

// ---------------------------------------------------------------- merged cast f32->bf16 (4 regions, 1 dispatch)
__global__ __launch_bounds__(256) void cast_all(
        const float* __restrict__ x,  const float* __restrict__ h,
        const float* __restrict__ wx, const float* __restrict__ wh,
        ushort* __restrict__ xb, ushort* __restrict__ hb,
        ushort* __restrict__ wxb, ushort* __restrict__ whb) {
    long i = ((long)blockIdx.x * 256 + threadIdx.x) * 8;
    const float* src; ushort* dst; long off;
    if      (i <  4194304L) { src = x;  dst = xb;  off = i; }
    else if (i < 12582912L) { src = h;  dst = hb;  off = i - 4194304L; }
    else if (i < 14680064L) { src = wx; dst = wxb; off = i - 12582912L; }
    else                    { src = wh; dst = whb; off = i - 14680064L; }
    const float4* p = (const float4*)(src + off);
    float4 a = p[0], b = p[1];
    uint4 r;
    r.x = (uint32_t)f2bf(a.x) | ((uint32_t)f2bf(a.y) << 16);
    r.y = (uint32_t)f2bf(a.z) | ((uint32_t)f2bf(a.w) << 16);
    r.z = (uint32_t)f2bf(b.x) | ((uint32_t)f2bf(b.y) << 16);
    r.w = (uint32_t)f2bf(b.z) | ((uint32_t)f2bf(b.w) << 16);
    *(uint4*)(dst + off) = r;
}

// ================================================================ 256x256 8-phase GEMM
// All dispatches are 256-block single-wave (1 block/CU), M split via m_base.
#define BAR()        __builtin_amdgcn_s_barrier()
#define SPRIO(x)     __builtin_amdgcn_s_setprio(x)
#define WAIT_LGKM0() do { asm volatile("s_waitcnt lgkmcnt(0)" ::: "memory"); \
                          __builtin_amdgcn_sched_barrier(0); } while (0)
#define WAIT_VM6()   do { asm volatile("s_waitcnt vmcnt(6)" ::: "memory"); \
                          __builtin_amdgcn_sched_barrier(0); } while (0)
#define WAIT_VM0()   do { asm volatile("s_waitcnt vmcnt(0)" ::: "memory"); \
                          __builtin_amdgcn_sched_barrier(0); } while (0)

template<int K>
__global__ __launch_bounds__(512, 2) void gemm256_8ph(
        const ushort* __restrict__ Ag,   // [M, K]
        const ushort* __restrict__ Bg,   // [GN, K]
        const float*  __restrict__ bias, // [GN]
        ushort* __restrict__ C,          // [M, GN]
        int GN, int m_base) {
    constexpr int NT = K / 64;           // K-tiles
    constexpr int NP = NT / 2;           // pair iterations

    __shared__ ushort lds[65536];        // 128 KiB: buf0{A,B} buf1{A,B}

    const int t    = threadIdx.x;        // 0..511
    const int lane = t & 63;
    const int w    = t >> 6;             // 0..7
    const int wr   = w >> 2;             // 0..1 (M half)
    const int wc   = w & 3;              // 0..3 (N quarter)
    const int ln   = lane & 15;
    const int hi   = lane >> 4;          // 0..3
    const int sx   = ln & 7;             // read-side XOR key (row&7 == ln&7)

    // XCD-aware bijective swizzle (gridDim.x % 8 == 0)
    const int bid = blockIdx.x;
    const int cpx = gridDim.x >> 3;
    const int wg  = (bid & 7) * cpx + (bid >> 3);
    const int n0  = (wg & 15) * 256;     // GN/256 = 16
    const int m0  = (wg >> 4) * 256 + m_base;

    // staging: thread t stages 16B; dst LINEAR; source col pre-swizzled.
    const int trow = t >> 3;                          // 0..63 within a 64-row load
    const int scol = (((t & 7) ^ (trow & 7)) * 8);    // shorts

#define STG_A(buf, j, kb) __builtin_amdgcn_global_load_lds( \
    (const __attribute__((address_space(1))) void*)(Ag + (size_t)(m0 + (j)*64 + trow) * K + (kb) + scol), \
    (__attribute__((address_space(3))) void*)(lds + (buf)*32768 + (j)*4096 + t*8), 16, 0, 0)
#define STG_B(buf, j, kb) __builtin_amdgcn_global_load_lds( \
    (const __attribute__((address_space(1))) void*)(Bg + (size_t)(n0 + (j)*64 + trow) * K + (kb) + scol), \
    (__attribute__((address_space(3))) void*)(lds + (buf)*32768 + 16384 + (j)*4096 + t*8), 16, 0, 0)

    // swizzled read offsets (shorts)
    const int ca0  = ((0 + hi) ^ sx) * 8;             // kk = 0
    const int ca1  = ((4 + hi) ^ sx) * 8;             // kk = 1
    const int arow = (wr * 16 + ln) * 64;             // + m*2048 (A frag m: rows m*32+wr*16+ln)
    const int brow = (wc * 16 + ln) * 64 + 16384;     // + n*4096 (B frag n: rows n*64+wc*16+ln)

    short8 af[2][4], bf0[2][2], bf1[2][2];
    f32x4  acc[8][4] = {};

#define LD_A(buf, mbase) do { _Pragma("unroll") for (int m = 0; m < 4; ++m) { \
    af[0][m] = *(const short8*)&lds[(buf)*32768 + arow + ((mbase)+m)*2048 + ca0]; \
    af[1][m] = *(const short8*)&lds[(buf)*32768 + arow + ((mbase)+m)*2048 + ca1]; } } while (0)
#define LD_B(dst, buf, nbase) do { _Pragma("unroll") for (int n = 0; n < 2; ++n) { \
    dst[0][n] = *(const short8*)&lds[(buf)*32768 + brow + ((nbase)+n)*4096 + ca0]; \
    dst[1][n] = *(const short8*)&lds[(buf)*32768 + brow + ((nbase)+n)*4096 + ca1]; } } while (0)
#define MMQ(mb, nb, B_) do { _Pragma("unroll") for (int kk = 0; kk < 2; ++kk) \
    _Pragma("unroll") for (int m = 0; m < 4; ++m) \
    _Pragma("unroll") for (int n = 0; n < 2; ++n) \
        acc[(mb)+m][(nb)+n] = __builtin_amdgcn_mfma_f32_16x16x32_bf16( \
            af[kk][m], B_[kk][n], acc[(mb)+m][(nb)+n], 0, 0, 0); } while (0)

    // ---- prologue: buf0 = tile0 (8 loads), buf1 = tile1 Bh0,Ah0,Bh1 (6 loads)
    STG_B(0,0,0);  STG_B(0,1,0);
    STG_A(0,0,0);  STG_A(0,1,0);
    STG_B(0,2,0);  STG_B(0,3,0);
    STG_A(0,2,0);  STG_A(0,3,0);
    STG_B(1,0,64); STG_B(1,1,64);
    STG_A(1,0,64); STG_A(1,1,64);
    STG_B(1,2,64); STG_B(1,3,64);
    WAIT_VM6(); BAR();

    // ---- main loop: iter p computes tiles 2p (buf0) and 2p+1 (buf1)
    for (int p = 0; p < NP; ++p) {
        const int k1 = (2*p + 1) * 64;
        const int t2 = (2*p + 2 < NT) ? (2*p + 2) : (2*p);
        const int t3 = (2*p + 3 < NT) ? (2*p + 3) : (2*p + 1);
        const int k2 = t2 * 64, k3 = t3 * 64;

        // P1: read buf0 Ah0+Bh0; stage buf1.Ah1
        LD_A(0, 0); LD_B(bf0, 0, 0);
        STG_A(1,2,k1); STG_A(1,3,k1);
        BAR(); WAIT_LGKM0();
        SPRIO(1); MMQ(0,0,bf0); SPRIO(0); BAR();
        // P2: read buf0 Bh1; stage buf0'.Bh0
        LD_B(bf1, 0, 2);
        STG_B(0,0,k2); STG_B(0,1,k2);
        BAR(); WAIT_LGKM0();
        SPRIO(1); MMQ(0,2,bf1); SPRIO(0); BAR();
        // P3: read buf0 Ah1; stage buf0'.Ah0
        LD_A(0, 4);
        STG_A(0,0,k2); STG_A(0,1,k2);
        BAR(); WAIT_LGKM0();
        SPRIO(1); MMQ(4,0,bf0); SPRIO(0); BAR();
        // P4: stage buf0'.Bh1; counted wait -> buf1 fully landed
        STG_B(0,2,k2); STG_B(0,3,k2);
        BAR();
        SPRIO(1); MMQ(4,2,bf1); SPRIO(0);
        WAIT_VM6(); BAR();
        // P5: read buf1 Ah0+Bh0; stage buf0'.Ah1
        LD_A(1, 0); LD_B(bf0, 1, 0);
        STG_A(0,2,k2); STG_A(0,3,k2);
        BAR(); WAIT_LGKM0();
        SPRIO(1); MMQ(0,0,bf0); SPRIO(0); BAR();
        // P6: read buf1 Bh1; stage buf1'.Bh0
        LD_B(bf1, 1, 2);
        STG_B(1,0,k3); STG_B(1,1,k3);
        BAR(); WAIT_LGKM0();
        SPRIO(1); MMQ(0,2,bf1); SPRIO(0); BAR();
        // P7: read buf1 Ah1; stage buf1'.Ah0
        LD_A(1, 4);
        STG_A(1,0,k3); STG_A(1,1,k3);
        BAR(); WAIT_LGKM0();
        SPRIO(1); MMQ(4,0,bf0); SPRIO(0); BAR();
        // P8: stage buf1'.Bh1; counted wait -> buf0' fully landed
        STG_B(1,2,k3); STG_B(1,3,k3);
        BAR();
        SPRIO(1); MMQ(4,2,bf1); SPRIO(0);
        WAIT_VM6(); BAR();
    }

    // ---- epilogue: stage C-tile in LDS (bf16, swizzled), then coalesced stores.
    WAIT_VM0();
    BAR();
#pragma unroll
    for (int n = 0; n < 4; ++n) {
        int cl   = n * 64 + wc * 16 + ln;
        float bv = bias[n0 + cl];
#pragma unroll
        for (int m = 0; m < 8; ++m) {
#pragma unroll
            for (int r = 0; r < 4; ++r) {
                int row = m * 32 + wr * 16 + hi * 4 + r;
                int sc  = (cl & 7) + ((((cl >> 3) ^ (row & 7))) << 3);
                lds[row * 256 + sc] = f2bf(acc[m][n][r] + bv);
            }
        }
    }
    BAR();
    {
        const int rr = t >> 5;
        const int oc = (t & 31) * 8;
#pragma unroll
        for (int i = 0; i < 16; ++i) {
            int row = i * 16 + rr;
            int sc  = (((oc >> 3) ^ (row & 7)) << 3);
            uint4 vv = *(const uint4*)&lds[row * 256 + sc];
            *(uint4*)(C + (size_t)(m0 + row) * GN + n0 + oc) = vv;
        }
    }
#undef STG_A
#undef STG_B
#undef LD_A
#undef LD_B
#undef MMQ
}

// ---------------------------------------------------------------- dual-row block reduce
// Both rows' butterflies interleaved (2x ILP in-wave), one barrier per round,
// non-volatile distinct per-round slices (barrier is the fence).
template<int NV>
__device__ __forceinline__ void reduce2(float* v0, float* v1, float* s0, float* s1) {
    const int lane = threadIdx.x & 63;
    const int w    = threadIdx.x >> 6;
#pragma unroll
    for (int i = 0; i < NV; ++i) {
        float a = v0[i], b = v1[i];
#pragma unroll
        for (int m = 32; m > 0; m >>= 1) {
            a += __shfl_xor(a, m, 64);
            b += __shfl_xor(b, m, 64);
        }
        if (lane == 0) { s0[i * 4 + w] = a; s1[i * 4 + w] = b; }
    }
    __syncthreads();
#pragma unroll
    for (int i = 0; i < NV; ++i) {
        v0[i] = s0[i * 4 + 0] + s0[i * 4 + 1] + s0[i * 4 + 2] + s0[i * 4 + 3];
        v1[i] = s1[i * 4 + 0] + s1[i * 4 + 1] + s1[i * 4 + 2] + s1[i * 4 + 3];
    }
}

// ---------------------------------------------------------------- fused cell: 2 ROWS PER THREAD
// 256-thread block (4 waves) handles rows 2b, 2b+1. Each thread owns elems
// [t*4, t*4+4) of each gate quarter for BOTH rows -> 2x ILP between barriers,
// gamma/beta loads amortized over 2 rows. 4 barriers total (4 rounds).
__global__ __launch_bounds__(256) void fused_cell2(
        const ushort* __restrict__ U, const ushort* __restrict__ V,
        const float* __restrict__ c_prev,
        const float* __restrict__ g_in, const float* __restrict__ b_in,
        const float* __restrict__ g_hu, const float* __restrict__ b_hu,
        const float* __restrict__ g_c,  const float* __restrict__ b_c,
        const float* __restrict__ g_h,  const float* __restrict__ b_h,
        float* __restrict__ out_h, float* __restrict__ out_c) {
    __shared__ float sred[2][4][16];           // [row][round][slot]
    const int t  = threadIdx.x;
    const int c0 = t * 4;
    const int rb = blockIdx.x * 2;

    // --- issue all row-data loads up front (packed; unpack on use)
    uint2 uu[2][4], vv[2][4];
    float4 cp4[2];
#pragma unroll
    for (int rj = 0; rj < 2; ++rj) {
        const size_t rowG = (size_t)(rb + rj) * 4096;
#pragma unroll
        for (int q = 0; q < 4; ++q) {
            uu[rj][q] = *(const uint2*)(U + rowG + q * 1024 + c0);
            vv[rj][q] = *(const uint2*)(V + rowG + q * 1024 + c0);
        }
        cp4[rj] = *(const float4*)(c_prev + (size_t)(rb + rj) * 1024 + c0);
    }
    float4 gc4 = *(const float4*)(g_c + c0);
    float4 bc4 = *(const float4*)(b_c + c0);
    float4 gh4 = *(const float4*)(g_h + c0);
    float4 bh4 = *(const float4*)(b_h + c0);

    // --- R1: LN stats over 4096 for u and v, both rows
    float red0[4] = {0.f, 0.f, 0.f, 0.f};
    float red1[4] = {0.f, 0.f, 0.f, 0.f};
#pragma unroll
    for (int rj = 0; rj < 2; ++rj) {
        float* rd = rj ? red1 : red0;
#pragma unroll
        for (int q = 0; q < 4; ++q) {
            float u0 = bfbits2f(uu[rj][q].x << 16), u1 = bfbits2f(uu[rj][q].x & 0xFFFF0000u);
            float u2 = bfbits2f(uu[rj][q].y << 16), u3 = bfbits2f(uu[rj][q].y & 0xFFFF0000u);
            float v0 = bfbits2f(vv[rj][q].x << 16), v1 = bfbits2f(vv[rj][q].x & 0xFFFF0000u);
            float v2 = bfbits2f(vv[rj][q].y << 16), v3 = bfbits2f(vv[rj][q].y & 0xFFFF0000u);
            rd[0] += u0 + u1 + u2 + u3;
            rd[1] += u0 * u0 + u1 * u1 + u2 * u2 + u3 * u3;
            rd[2] += v0 + v1 + v2 + v3;
            rd[3] += v0 * v0 + v1 * v1 + v2 * v2 + v3 * v3;
        }
    }
    reduce2<4>(red0, red1, sred[0][0], sred[1][0]);
    const float inv4096 = 1.f / 4096.f;
    float mu_u[2], rs_u[2], mu_v[2], rs_v[2];
    mu_u[0] = red0[0] * inv4096; mu_v[0] = red0[2] * inv4096;
    rs_u[0] = frsq(red0[1] * inv4096 - mu_u[0] * mu_u[0] + LN_EPS);
    rs_v[0] = frsq(red0[3] * inv4096 - mu_v[0] * mu_v[0] + LN_EPS);
    mu_u[1] = red1[0] * inv4096; mu_v[1] = red1[2] * inv4096;
    rs_u[1] = frsq(red1[1] * inv4096 - mu_u[1] * mu_u[1] + LN_EPS);
    rs_v[1] = frsq(red1[3] * inv4096 - mu_v[1] * mu_v[1] + LN_EPS);

    // --- gates = LN(u)*g1+b1 + LN(v)*g2+b2 (params loaded once per quarter)
    float gate[2][4][4];
#pragma unroll
    for (int q = 0; q < 4; ++q) {
        const int idx = q * 1024 + c0;
        float4 ga = *(const float4*)(g_in + idx);
        float4 ba = *(const float4*)(b_in + idx);
        float4 gb = *(const float4*)(g_hu + idx);
        float4 bb = *(const float4*)(b_hu + idx);
        float gaa[4] = {ga.x, ga.y, ga.z, ga.w};
        float baa[4] = {ba.x, ba.y, ba.z, ba.w};
        float gba[4] = {gb.x, gb.y, gb.z, gb.w};
        float bba[4] = {bb.x, bb.y, bb.z, bb.w};
#pragma unroll
        for (int rj = 0; rj < 2; ++rj) {
            float uf[4], vf[4];
            uf[0] = bfbits2f(uu[rj][q].x << 16); uf[1] = bfbits2f(uu[rj][q].x & 0xFFFF0000u);
            uf[2] = bfbits2f(uu[rj][q].y << 16); uf[3] = bfbits2f(uu[rj][q].y & 0xFFFF0000u);
            vf[0] = bfbits2f(vv[rj][q].x << 16); vf[1] = bfbits2f(vv[rj][q].x & 0xFFFF0000u);
            vf[2] = bfbits2f(vv[rj][q].y << 16); vf[3] = bfbits2f(vv[rj][q].y & 0xFFFF0000u);
#pragma unroll
            for (int j = 0; j < 4; ++j) {
                float zu = (uf[j] - mu_u[rj]) * rs_u[rj];
                float zv = (vf[j] - mu_v[rj]) * rs_v[rj];
                gate[rj][q][j] = zu * gaa[j] + baa[j] + zv * gba[j] + bba[j];
            }
        }
    }

    // --- R2: exp sums (shift-invariant softmax; +-20 inf-guard never binds)
    float ei[2][4], ef[2][4];
    red0[0] = red0[1] = red1[0] = red1[1] = 0.f;
#pragma unroll
    for (int rj = 0; rj < 2; ++rj) {
        float* rd = rj ? red1 : red0;
#pragma unroll
        for (int q = 0; q < 4; ++q) {
            ei[rj][q] = fexp(fminf(fmaxf(gate[rj][0][q], -20.f), 20.f));
            ef[rj][q] = fexp(fminf(fmaxf(gate[rj][1][q], -20.f), 20.f));
            rd[0] += ei[rj][q]; rd[1] += ef[rj][q];
        }
    }
    reduce2<2>(red0, red1, sred[0][1], sred[1][1]);
    float inv_si[2], inv_sf[2];
    inv_si[0] = frcp(red0[0] + EPS_CELL); inv_sf[0] = frcp(red0[1] + EPS_CELL);
    inv_si[1] = frcp(red1[0] + EPS_CELL); inv_sf[1] = frcp(red1[1] + EPS_CELL);

    // --- cell update
    float cpv[2][4];
    red0[0] = red0[1] = red1[0] = red1[1] = 0.f;
#pragma unroll
    for (int rj = 0; rj < 2; ++rj) {
        float* rd = rj ? red1 : red0;
        float cpr[4] = {cp4[rj].x, cp4[rj].y, cp4[rj].z, cp4[rj].w};
#pragma unroll
        for (int q = 0; q < 4; ++q) {
            float in_ = ei[rj][q] * inv_si[rj];
            float fn_ = ef[rj][q] * inv_sf[rj];
            float den = frcp(in_ + fn_ + EPS_CELL);
            cpv[rj][q] = fn_ * den * cpr[q] + in_ * den * ftanh(gate[rj][2][q]);
            rd[0] += cpv[rj][q]; rd[1] += cpv[rj][q] * cpv[rj][q];
        }
    }
    reduce2<2>(red0, red1, sred[0][2], sred[1][2]);
    const float inv1024 = 1.f / 1024.f;
    float mu_c[2], rs_c[2];
    mu_c[0] = red0[0] * inv1024;
    rs_c[0] = frsq(red0[1] * inv1024 - mu_c[0] * mu_c[0] + LN_EPS);
    mu_c[1] = red1[0] * inv1024;
    rs_c[1] = frsq(red1[1] * inv1024 - mu_c[1] * mu_c[1] + LN_EPS);

    // --- c-LN, write c, tanh stats
    float th[2][4];
    {
        float gca[4] = {gc4.x, gc4.y, gc4.z, gc4.w};
        float bca[4] = {bc4.x, bc4.y, bc4.z, bc4.w};
        red0[0] = red0[1] = red1[0] = red1[1] = 0.f;
#pragma unroll
        for (int rj = 0; rj < 2; ++rj) {
            float* rd = rj ? red1 : red0;
            float cv[4];
#pragma unroll
            for (int q = 0; q < 4; ++q) {
                cv[q] = (cpv[rj][q] - mu_c[rj]) * rs_c[rj] * gca[q] + bca[q];
                th[rj][q] = ftanh(cv[q]);
                rd[0] += th[rj][q]; rd[1] += th[rj][q] * th[rj][q];
            }
            float4 o; o.x = cv[0]; o.y = cv[1]; o.z = cv[2]; o.w = cv[3];
            *(float4*)(out_c + (size_t)(rb + rj) * 1024 + c0) = o;
        }
    }
    reduce2<2>(red0, red1, sred[0][3], sred[1][3]);
    float mu_t[2], rs_t[2];
    mu_t[0] = red0[0] * inv1024;
    rs_t[0] = frsq(red0[1] * inv1024 - mu_t[0] * mu_t[0] + LN_EPS);
    mu_t[1] = red1[0] * inv1024;
    rs_t[1] = frsq(red1[1] * inv1024 - mu_t[1] * mu_t[1] + LN_EPS);

    // --- h output
    {
        float gha[4] = {gh4.x, gh4.y, gh4.z, gh4.w};
        float bha[4] = {bh4.x, bh4.y, bh4.z, bh4.w};
#pragma unroll
        for (int rj = 0; rj < 2; ++rj) {
            float hv[4];
#pragma unroll
            for (int q = 0; q < 4; ++q) {
                float co = (th[rj][q] - mu_t[rj]) * rs_t[rj] * gha[q] + bha[q];
                hv[q] = fsigm(gate[rj][3][q]) * co;
            }
            float4 o; o.x = hv[0]; o.y = hv[1]; o.z = hv[2]; o.w = hv[3];
            *(float4*)(out_h + (size_t)(rb + rj) * 1024 + c0) = o;
        }
    }
}

// ---------------------------------------------------------------- launch
extern "C" void kernel_launch(void* const* d_in, const int* in_sizes, int n_in,
                              void* d_out, int out_size, void* d_ws, size_t ws_size,
                              hipStream_t stream) {
    const float* x       = (const float*)d_in[0];
    const float* h_prev  = (const float*)d_in[1];
    const float* c_prev  = (const float*)d_in[2];
    const float* Wx      = (const float*)d_in[3];
    const float* bx      = (const float*)d_in[4];
    const float* Wh      = (const float*)d_in[5];
    const float* bh      = (const float*)d_in[6];
    const float* ln_in_g = (const float*)d_in[7];
    const float* ln_in_b = (const float*)d_in[8];
    const float* ln_hu_g = (const float*)d_in[9];
    const float* ln_hu_b = (const float*)d_in[10];
    const float* ln_c_g  = (const float*)d_in[11];
    const float* ln_c_b  = (const float*)d_in[12];
    const float* ln_h_g  = (const float*)d_in[13];
    const float* ln_h_b  = (const float*)d_in[14];

    const int B = 8192, Din = 512, H = 1024, G = 4096;

    ushort* xb  = (ushort*)d_ws;                  // B*Din
    ushort* hb  = xb  + (size_t)B * Din;          // B*H
    ushort* wxb = hb  + (size_t)B * H;            // G*Din
    ushort* whb = wxb + (size_t)G * Din;          // G*H
    ushort* U   = whb + (size_t)G * H;            // B*G
    ushort* V   = U   + (size_t)B * G;            // B*G

    // one merged cast dispatch
    cast_all<<<9216, 256, 0, stream>>>(x, h_prev, Wx, Wh, xb, hb, wxb, whb);

    // all four GEMM dispatches: 256-block single-wave (measured-best config, r7)
    gemm256_8ph<512> <<<dim3(256), 512, 0, stream>>>(xb, wxb, bx, U, G, 0);
    gemm256_8ph<512> <<<dim3(256), 512, 0, stream>>>(xb, wxb, bx, U, G, 4096);
    gemm256_8ph<1024><<<dim3(256), 512, 0, stream>>>(hb, whb, bh, V, G, 0);
    gemm256_8ph<1024><<<dim3(256), 512, 0, stream>>>(hb, whb, bh, V, G, 4096);

    float* out_h = (float*)d_out;
    float* out_c = out_h + (size_t)B * H;
    fused_cell2<<<B / 2, 256, 0, stream>>>(U, V, c_prev,
                                           ln_in_g, ln_in_b, ln_hu_g, ln_hu_b,
                                           ln_c_g, ln_c_b, ln_h_g, ln_h_b,
                                           out_h, out_c);
}